// Round 1
// baseline (661.548 us; speedup 1.0000x reference)
//
#include <hip/hip_runtime.h>

// GCN 3-layer + edge scorer for MI355X.
// Pipeline: degree count -> dinv -> CSR build (scan + scatter) ->
//   3x [GEMM(*dinv epilogue) -> CSR aggregate(+bias, relu)] ->
//   per-node Wc dots -> per-edge a[src]+b[dst]+bc.

static __device__ __forceinline__ float4 f4add(float4 a, float4 b) {
    return make_float4(a.x + b.x, a.y + b.y, a.z + b.z, a.w + b.w);
}

__global__ __launch_bounds__(256) void count_deg(const int* __restrict__ dst,
                                                 int* __restrict__ cnt, int E) {
    int e = blockIdx.x * 256 + threadIdx.x;
    if (e < E) atomicAdd(&cnt[dst[e]], 1);
}

__global__ __launch_bounds__(256) void compute_dinv(const int* __restrict__ cnt,
                                                    float* __restrict__ dinv, int N) {
    int i = blockIdx.x * 256 + threadIdx.x;
    if (i < N) dinv[i] = rsqrtf((float)(cnt[i] + 1));  // +1 self loop; deg>=1 always
}

__global__ __launch_bounds__(256) void scan1(const int* __restrict__ cnt,
                                             int* __restrict__ rowp,
                                             int* __restrict__ bsum, int N) {
    __shared__ int s[256];
    int t = threadIdx.x;
    int i = blockIdx.x * 256 + t;
    int v = (i < N) ? cnt[i] : 0;
    s[t] = v;
    __syncthreads();
    #pragma unroll
    for (int off = 1; off < 256; off <<= 1) {
        int add = (t >= off) ? s[t - off] : 0;
        __syncthreads();
        s[t] += add;
        __syncthreads();
    }
    if (i < N) rowp[i] = s[t] - v;          // exclusive within block
    if (t == 255) bsum[blockIdx.x] = s[255]; // block total
}

__global__ __launch_bounds__(512) void scan2(int* __restrict__ bsum, int NB) {
    __shared__ int s[512];
    int t = threadIdx.x;
    int v = (t < NB) ? bsum[t] : 0;
    s[t] = v;
    __syncthreads();
    #pragma unroll
    for (int off = 1; off < 512; off <<= 1) {
        int add = (t >= off) ? s[t - off] : 0;
        __syncthreads();
        s[t] += add;
        __syncthreads();
    }
    if (t < NB) bsum[t] = s[t] - v;          // exclusive block offsets
}

__global__ __launch_bounds__(256) void scan3(int* __restrict__ rowp,
                                             const int* __restrict__ bsum,
                                             int* __restrict__ cursor, int N) {
    int i = blockIdx.x * 256 + threadIdx.x;
    if (i < N) {
        int v = rowp[i] + bsum[blockIdx.x];
        rowp[i] = v;
        cursor[i] = v;
    }
}

__global__ __launch_bounds__(256) void scatter_edges(const int* __restrict__ src,
                                                     const int* __restrict__ dst,
                                                     int* __restrict__ cursor,
                                                     int* __restrict__ ssrc, int E) {
    int e = blockIdx.x * 256 + threadIdx.x;
    if (e < E) {
        int pos = atomicAdd(&cursor[dst[e]], 1);
        ssrc[pos] = src[e];
    }
    // post-condition: cursor[d] == rowp[d+1] (row end) -- used by aggregate
}

// G[i][j] = (sum_k X[i][k] * W[k][j]) * dinv[i]
// Block: 64 rows staged in LDS; 256 threads; thread owns JT columns x RPT rows.
template <int FIN, int FOUT, int JG, int JT>
__global__ __launch_bounds__(256) void gemm_dinv(const float* __restrict__ X,
                                                 const float* __restrict__ W,
                                                 const float* __restrict__ dinv,
                                                 float* __restrict__ G, int N) {
    constexpr int ROWS = 64;
    constexpr int GROUPS = 256 / JG;
    constexpr int RPT = ROWS / GROUPS;
    __shared__ float xs[ROWS * FIN];
    const int t = threadIdx.x;
    const int r0 = blockIdx.x * ROWS;

    // stage 64 x FIN tile of X (zeros for out-of-range rows)
    constexpr int NV = ROWS * FIN / 4;
    const float4* X4 = reinterpret_cast<const float4*>(X + (size_t)r0 * FIN);
    float4* xs4 = reinterpret_cast<float4*>(xs);
    #pragma unroll
    for (int v = t; v < NV; v += 256) {
        int row = v / (FIN / 4);
        float4 val = make_float4(0.f, 0.f, 0.f, 0.f);
        if (r0 + row < N) val = X4[v];
        xs4[v] = val;
    }
    __syncthreads();

    const int jg = t % JG;
    const int grp = t / JG;
    float acc[RPT][JT];
    #pragma unroll
    for (int r = 0; r < RPT; r++)
        #pragma unroll
        for (int jj = 0; jj < JT; jj++) acc[r][jj] = 0.f;

    for (int k0 = 0; k0 < FIN; k0 += 8) {
        float wr[8][JT];
        #pragma unroll
        for (int q = 0; q < 8; q++)
            #pragma unroll
            for (int jj = 0; jj < JT; jj++)
                wr[q][jj] = W[(k0 + q) * FOUT + jg + jj * JG];
        #pragma unroll
        for (int r = 0; r < RPT; r++) {
            const int lr = grp * RPT + r;
            float xv[8];
            #pragma unroll
            for (int q = 0; q < 8; q++) xv[q] = xs[lr * FIN + k0 + q];
            #pragma unroll
            for (int q = 0; q < 8; q++)
                #pragma unroll
                for (int jj = 0; jj < JT; jj++)
                    acc[r][jj] += xv[q] * wr[q][jj];
        }
    }

    #pragma unroll
    for (int r = 0; r < RPT; r++) {
        const int gr = r0 + grp * RPT + r;
        if (gr < N) {
            const float dv = dinv[gr];
            #pragma unroll
            for (int jj = 0; jj < JT; jj++)
                G[(size_t)gr * FOUT + jg + jj * JG] = acc[r][jj] * dv;
        }
    }
}

// H[d] = relu(dinv[d] * (G[d] + sum_{e in row d} G[ssrc[e]]) + bias)
template <int F>
__global__ __launch_bounds__(256) void aggregate(const float* __restrict__ G,
                                                 const int* __restrict__ rowp,
                                                 const int* __restrict__ rowe,
                                                 const int* __restrict__ ssrc,
                                                 const float* __restrict__ dinv,
                                                 const float* __restrict__ bias,
                                                 float* __restrict__ H, int N) {
    constexpr int L = F / 4;        // lanes per node (float4 each)
    constexpr int NPB = 256 / L;    // nodes per block
    const int t = threadIdx.x;
    const int lj = t % L;
    const int d = blockIdx.x * NPB + t / L;
    if (d >= N) return;

    const float4* G4 = reinterpret_cast<const float4*>(G);
    float4 acc = G4[(size_t)d * L + lj];   // self-loop contribution
    int e = rowp[d];
    const int end = rowe[d];
    for (; e + 4 <= end; e += 4) {
        int s0 = ssrc[e], s1 = ssrc[e + 1], s2 = ssrc[e + 2], s3 = ssrc[e + 3];
        float4 v0 = G4[(size_t)s0 * L + lj];
        float4 v1 = G4[(size_t)s1 * L + lj];
        float4 v2 = G4[(size_t)s2 * L + lj];
        float4 v3 = G4[(size_t)s3 * L + lj];
        acc = f4add(acc, f4add(f4add(v0, v1), f4add(v2, v3)));
    }
    for (; e < end; e++) {
        int s = ssrc[e];
        acc = f4add(acc, G4[(size_t)s * L + lj]);
    }
    const float dv = dinv[d];
    const float4 b4 = reinterpret_cast<const float4*>(bias)[lj];
    float4 h;
    h.x = fmaxf(acc.x * dv + b4.x, 0.f);
    h.y = fmaxf(acc.y * dv + b4.y, 0.f);
    h.z = fmaxf(acc.z * dv + b4.z, 0.f);
    h.w = fmaxf(acc.w * dv + b4.w, 0.f);
    reinterpret_cast<float4*>(H)[(size_t)d * L + lj] = h;
}

// a[i] = H[i][0:32] . Wc[0:32] ; b[i] = H[i][0:32] . Wc[32:64]
__global__ __launch_bounds__(256) void node_scores(const float* __restrict__ H,
                                                   const float* __restrict__ Wc,
                                                   float* __restrict__ aArr,
                                                   float* __restrict__ bArr, int N) {
    const int t = threadIdx.x;
    const int lane = t % 32;
    const int i = blockIdx.x * 8 + t / 32;
    if (i >= N) return;
    const float h = H[(size_t)i * 32 + lane];
    float p = h * Wc[lane];
    float q = h * Wc[32 + lane];
    #pragma unroll
    for (int off = 16; off > 0; off >>= 1) {
        p += __shfl_xor(p, off, 32);
        q += __shfl_xor(q, off, 32);
    }
    if (lane == 0) {
        aArr[i] = p;
        bArr[i] = q;
    }
}

__global__ __launch_bounds__(256) void edge_out(const int* __restrict__ src,
                                                const int* __restrict__ dst,
                                                const float* __restrict__ aArr,
                                                const float* __restrict__ bArr,
                                                const float* __restrict__ bc,
                                                float* __restrict__ out, int E) {
    int e = blockIdx.x * 256 + threadIdx.x;
    if (e < E) out[e] = aArr[src[e]] + bArr[dst[e]] + bc[0];
}

extern "C" void kernel_launch(void* const* d_in, const int* in_sizes, int n_in,
                              void* d_out, int out_size, void* d_ws, size_t ws_size,
                              hipStream_t stream) {
    const float* x  = (const float*)d_in[0];
    const int*   ei = (const int*)d_in[1];   // int64 in ref; harness delivers int32
    const float* W1 = (const float*)d_in[2];
    const float* b1 = (const float*)d_in[3];
    const float* W2 = (const float*)d_in[4];
    const float* b2 = (const float*)d_in[5];
    const float* W3 = (const float*)d_in[6];
    const float* b3 = (const float*)d_in[7];
    const float* Wc = (const float*)d_in[8];
    const float* bc = (const float*)d_in[9];
    float* out = (float*)d_out;

    const int N = in_sizes[0] / 128;   // 100000
    const int E = in_sizes[1] / 2;     // 1600000
    const int* src = ei;
    const int* dst = ei + E;

    // workspace carve-out (~111 MB total)
    size_t off = 0;
    auto alloc = [&](size_t bytes) -> void* {
        size_t o = (off + 255) & ~(size_t)255;
        off = o + bytes;
        return (void*)((char*)d_ws + o);
    };
    float* dinv = (float*)alloc((size_t)N * 4);
    int*   cnt  = (int*)alloc((size_t)N * 4);    // counts, later CSR cursors/row-ends
    int*   rowp = (int*)alloc((size_t)N * 4);
    int*   bsum = (int*)alloc(4096);
    int*   ssrc = (int*)alloc((size_t)E * 4);
    float* bufA = (float*)alloc((size_t)N * 128 * 4);
    float* bufB = (float*)alloc((size_t)N * 128 * 4);
    float* aArr = (float*)alloc((size_t)N * 4);
    float* bArr = (float*)alloc((size_t)N * 4);
    (void)ws_size; (void)n_in; (void)out_size;

    const int gE = (E + 255) / 256;
    const int gN = (N + 255) / 256;   // 391 blocks, fits scan2's 512 slots
    const int gR = (N + 63) / 64;

    hipMemsetAsync(cnt, 0, (size_t)N * 4, stream);
    count_deg<<<gE, 256, 0, stream>>>(dst, cnt, E);
    compute_dinv<<<gN, 256, 0, stream>>>(cnt, dinv, N);
    scan1<<<gN, 256, 0, stream>>>(cnt, rowp, bsum, N);
    scan2<<<1, 512, 0, stream>>>(bsum, gN);
    scan3<<<gN, 256, 0, stream>>>(rowp, bsum, cnt, N);
    scatter_edges<<<gE, 256, 0, stream>>>(src, dst, cnt, ssrc, E);

    // layer 1: x(128) -> h1(128)
    gemm_dinv<128, 128, 64, 2><<<gR, 256, 0, stream>>>(x, W1, dinv, bufA, N);
    aggregate<128><<<(N + 7) / 8, 256, 0, stream>>>(bufA, rowp, cnt, ssrc, dinv, b1, bufB, N);
    // layer 2: h1(128) -> h2(64)
    gemm_dinv<128, 64, 32, 2><<<gR, 256, 0, stream>>>(bufB, W2, dinv, bufA, N);
    aggregate<64><<<(N + 15) / 16, 256, 0, stream>>>(bufA, rowp, cnt, ssrc, dinv, b2, bufB, N);
    // layer 3: h2(64) -> h3(32)
    gemm_dinv<64, 32, 32, 1><<<gR, 256, 0, stream>>>(bufB, W3, dinv, bufA, N);
    aggregate<32><<<(N + 31) / 32, 256, 0, stream>>>(bufA, rowp, cnt, ssrc, dinv, b3, bufB, N);

    // edge scoring
    node_scores<<<(N + 7) / 8, 256, 0, stream>>>(bufB, Wc, aArr, bArr, N);
    edge_out<<<gE, 256, 0, stream>>>(src, dst, aArr, bArr, bc, out, E);
}

// Round 2
// 539.281 us; speedup vs baseline: 1.2267x; 1.2267x over previous
//
#include <hip/hip_runtime.h>

// GCN 3-layer + edge scorer for MI355X.
// Pipeline: bucket-binned CSR build (hist -> scan -> bin -> per-bucket build)
//   -> 3x [GEMM(*dinv epilogue) -> CSR aggregate(+bias, relu)]
//   -> per-node Wc dots -> per-edge a[src]+b[dst]+bc.
//
// R2: replaced atomic-cursor scatter (132us, 105MB write-amplified HBM traffic
// = 1.6M random 4B stores x 64B lines) with a 2-phase counting sort whose
// write windows stay L2-resident so lines combine before eviction.

#define BSHIFT 8                      // bucket = dst >> 8  (256 nodes/bucket)
#define MAXB   512                    // LDS sizing; actual B = ceil(N/256) = 391

static __device__ __forceinline__ float4 f4add(float4 a, float4 b) {
    return make_float4(a.x + b.x, a.y + b.y, a.z + b.z, a.w + b.w);
}

// Phase A1: per-bucket edge histogram (LDS-staged to avoid 4096-way global
// atomic contention per counter).
__global__ __launch_bounds__(256) void bucket_hist(const int* __restrict__ dst,
                                                   int* __restrict__ bcnt,
                                                   int E, int B) {
    __shared__ int h[MAXB];
    const int t = threadIdx.x;
    for (int i = t; i < B; i += 256) h[i] = 0;
    __syncthreads();
    for (int e = blockIdx.x * 256 + t; e < E; e += gridDim.x * 256)
        atomicAdd(&h[dst[e] >> BSHIFT], 1);
    __syncthreads();
    for (int i = t; i < B; i += 256) {
        int c = h[i];
        if (c) atomicAdd(&bcnt[i], c);
    }
}

// Phase A1b: exclusive scan of bucket counts -> boff[0..B], init cursors.
__global__ __launch_bounds__(512) void scan_buckets(const int* __restrict__ bcnt,
                                                    int* __restrict__ boff,
                                                    int* __restrict__ bcur,
                                                    int B, int E) {
    __shared__ int s[512];
    const int t = threadIdx.x;
    int v = (t < B) ? bcnt[t] : 0;
    s[t] = v;
    __syncthreads();
    #pragma unroll
    for (int off = 1; off < 512; off <<= 1) {
        int add = (t >= off) ? s[t - off] : 0;
        __syncthreads();
        s[t] += add;
        __syncthreads();
    }
    if (t < B) {
        int excl = s[t] - v;
        boff[t] = excl;
        bcur[t] = excl;
    }
    if (t == B - 1) boff[B] = E;
}

// Phase A2: bin (src,dst) pairs into bucket-contiguous segments. Per-block
// hot write window = B x 64B cursor lines (~25KB) -> L2 write-combines.
#define BIN_CHUNK 8192
__global__ __launch_bounds__(256) void bin_edges(const int* __restrict__ src,
                                                 const int* __restrict__ dst,
                                                 int* __restrict__ bcur,
                                                 uint2* __restrict__ pairs,
                                                 int E, int B) {
    __shared__ int h[MAXB];
    __shared__ int base[MAXB];
    const int t = threadIdx.x;
    const int e0 = blockIdx.x * BIN_CHUNK;
    const int eEnd = min(e0 + BIN_CHUNK, E);
    for (int i = t; i < B; i += 256) h[i] = 0;
    __syncthreads();
    for (int e = e0 + t; e < eEnd; e += 256)
        atomicAdd(&h[dst[e] >> BSHIFT], 1);
    __syncthreads();
    for (int i = t; i < B; i += 256) {
        int c = h[i];
        base[i] = c ? atomicAdd(&bcur[i], c) : 0;
        h[i] = 0;
    }
    __syncthreads();
    for (int e = e0 + t; e < eEnd; e += 256) {
        int d = dst[e];
        int b = d >> BSHIFT;
        int pos = base[b] + atomicAdd(&h[b], 1);
        pairs[pos] = make_uint2((unsigned)src[e], (unsigned)d);
    }
}

// Phase B: one block per bucket. LDS per-node hist -> scan -> rowp/rowe/dinv
// -> scatter src into the bucket's 16KB ssrc window (L2-combined writes).
__global__ __launch_bounds__(256) void build_csr(const uint2* __restrict__ pairs,
                                                 const int* __restrict__ boff,
                                                 int* __restrict__ rowp,
                                                 int* __restrict__ rowe,
                                                 float* __restrict__ dinv,
                                                 int* __restrict__ ssrc, int N) {
    __shared__ int s[256];
    __shared__ int cur[256];
    const int t = threadIdx.x;
    const int b = blockIdx.x;
    const int eBeg = boff[b], eEnd = boff[b + 1];
    const int nodeBase = b << BSHIFT;
    s[t] = 0;
    __syncthreads();
    for (int e = eBeg + t; e < eEnd; e += 256)
        atomicAdd(&s[pairs[e].y - nodeBase], 1);
    __syncthreads();
    const int v = s[t];  // degree (w/o self loop) of node nodeBase+t
    #pragma unroll
    for (int off = 1; off < 256; off <<= 1) {
        int add = (t >= off) ? s[t - off] : 0;
        __syncthreads();
        s[t] += add;
        __syncthreads();
    }
    const int rp = eBeg + s[t] - v;  // exclusive
    const int node = nodeBase + t;
    if (node < N) {
        rowp[node] = rp;
        rowe[node] = rp + v;
        dinv[node] = rsqrtf((float)(v + 1));
    }
    cur[t] = rp;
    __syncthreads();
    for (int e = eBeg + t; e < eEnd; e += 256) {
        uint2 p = pairs[e];
        int pos = atomicAdd(&cur[p.y - nodeBase], 1);
        ssrc[pos] = (int)p.x;
    }
}

// G[i][j] = (sum_k X[i][k] * W[k][j]) * dinv[i]
template <int FIN, int FOUT, int JG, int JT>
__global__ __launch_bounds__(256) void gemm_dinv(const float* __restrict__ X,
                                                 const float* __restrict__ W,
                                                 const float* __restrict__ dinv,
                                                 float* __restrict__ G, int N) {
    constexpr int ROWS = 64;
    constexpr int GROUPS = 256 / JG;
    constexpr int RPT = ROWS / GROUPS;
    __shared__ float xs[ROWS * FIN];
    const int t = threadIdx.x;
    const int r0 = blockIdx.x * ROWS;

    constexpr int NV = ROWS * FIN / 4;
    const float4* X4 = reinterpret_cast<const float4*>(X + (size_t)r0 * FIN);
    float4* xs4 = reinterpret_cast<float4*>(xs);
    #pragma unroll
    for (int v = t; v < NV; v += 256) {
        int row = v / (FIN / 4);
        float4 val = make_float4(0.f, 0.f, 0.f, 0.f);
        if (r0 + row < N) val = X4[v];
        xs4[v] = val;
    }
    __syncthreads();

    const int jg = t % JG;
    const int grp = t / JG;
    float acc[RPT][JT];
    #pragma unroll
    for (int r = 0; r < RPT; r++)
        #pragma unroll
        for (int jj = 0; jj < JT; jj++) acc[r][jj] = 0.f;

    for (int k0 = 0; k0 < FIN; k0 += 8) {
        float wr[8][JT];
        #pragma unroll
        for (int q = 0; q < 8; q++)
            #pragma unroll
            for (int jj = 0; jj < JT; jj++)
                wr[q][jj] = W[(k0 + q) * FOUT + jg + jj * JG];
        #pragma unroll
        for (int r = 0; r < RPT; r++) {
            const int lr = grp * RPT + r;
            float xv[8];
            #pragma unroll
            for (int q = 0; q < 8; q++) xv[q] = xs[lr * FIN + k0 + q];
            #pragma unroll
            for (int q = 0; q < 8; q++)
                #pragma unroll
                for (int jj = 0; jj < JT; jj++)
                    acc[r][jj] += xv[q] * wr[q][jj];
        }
    }

    #pragma unroll
    for (int r = 0; r < RPT; r++) {
        const int gr = r0 + grp * RPT + r;
        if (gr < N) {
            const float dv = dinv[gr];
            #pragma unroll
            for (int jj = 0; jj < JT; jj++)
                G[(size_t)gr * FOUT + jg + jj * JG] = acc[r][jj] * dv;
        }
    }
}

// H[d] = relu(dinv[d] * (G[d] + sum_{e in row d} G[ssrc[e]]) + bias)
template <int F>
__global__ __launch_bounds__(256) void aggregate(const float* __restrict__ G,
                                                 const int* __restrict__ rowp,
                                                 const int* __restrict__ rowe,
                                                 const int* __restrict__ ssrc,
                                                 const float* __restrict__ dinv,
                                                 const float* __restrict__ bias,
                                                 float* __restrict__ H, int N) {
    constexpr int L = F / 4;        // float4 lanes per node
    constexpr int NPB = 256 / L;
    const int t = threadIdx.x;
    const int lj = t % L;
    const int d = blockIdx.x * NPB + t / L;
    if (d >= N) return;

    const float4* G4 = reinterpret_cast<const float4*>(G);
    float4 acc = G4[(size_t)d * L + lj];   // self-loop
    int e = rowp[d];
    const int end = rowe[d];
    for (; e + 4 <= end; e += 4) {
        int s0 = ssrc[e], s1 = ssrc[e + 1], s2 = ssrc[e + 2], s3 = ssrc[e + 3];
        float4 v0 = G4[(size_t)s0 * L + lj];
        float4 v1 = G4[(size_t)s1 * L + lj];
        float4 v2 = G4[(size_t)s2 * L + lj];
        float4 v3 = G4[(size_t)s3 * L + lj];
        acc = f4add(acc, f4add(f4add(v0, v1), f4add(v2, v3)));
    }
    for (; e < end; e++)
        acc = f4add(acc, G4[(size_t)ssrc[e] * L + lj]);
    const float dv = dinv[d];
    const float4 b4 = reinterpret_cast<const float4*>(bias)[lj];
    float4 h;
    h.x = fmaxf(acc.x * dv + b4.x, 0.f);
    h.y = fmaxf(acc.y * dv + b4.y, 0.f);
    h.z = fmaxf(acc.z * dv + b4.z, 0.f);
    h.w = fmaxf(acc.w * dv + b4.w, 0.f);
    reinterpret_cast<float4*>(H)[(size_t)d * L + lj] = h;
}

// a[i] = H[i][0:32].Wc[0:32] ; b[i] = H[i][0:32].Wc[32:64]
__global__ __launch_bounds__(256) void node_scores(const float* __restrict__ H,
                                                   const float* __restrict__ Wc,
                                                   float* __restrict__ aArr,
                                                   float* __restrict__ bArr, int N) {
    const int t = threadIdx.x;
    const int lane = t % 32;
    const int i = blockIdx.x * 8 + t / 32;
    if (i >= N) return;
    const float h = H[(size_t)i * 32 + lane];
    float p = h * Wc[lane];
    float q = h * Wc[32 + lane];
    #pragma unroll
    for (int off = 16; off > 0; off >>= 1) {
        p += __shfl_xor(p, off, 32);
        q += __shfl_xor(q, off, 32);
    }
    if (lane == 0) {
        aArr[i] = p;
        bArr[i] = q;
    }
}

__global__ __launch_bounds__(256) void edge_out(const int* __restrict__ src,
                                                const int* __restrict__ dst,
                                                const float* __restrict__ aArr,
                                                const float* __restrict__ bArr,
                                                const float* __restrict__ bc,
                                                float* __restrict__ out, int E) {
    int e = blockIdx.x * 256 + threadIdx.x;
    if (e < E) out[e] = aArr[src[e]] + bArr[dst[e]] + bc[0];
}

extern "C" void kernel_launch(void* const* d_in, const int* in_sizes, int n_in,
                              void* d_out, int out_size, void* d_ws, size_t ws_size,
                              hipStream_t stream) {
    const float* x  = (const float*)d_in[0];
    const int*   ei = (const int*)d_in[1];
    const float* W1 = (const float*)d_in[2];
    const float* b1 = (const float*)d_in[3];
    const float* W2 = (const float*)d_in[4];
    const float* b2 = (const float*)d_in[5];
    const float* W3 = (const float*)d_in[6];
    const float* b3 = (const float*)d_in[7];
    const float* Wc = (const float*)d_in[8];
    const float* bc = (const float*)d_in[9];
    float* out = (float*)d_out;

    const int N = in_sizes[0] / 128;   // 100000
    const int E = in_sizes[1] / 2;     // 1600000
    const int B = (N + 255) >> BSHIFT; // 391 buckets
    const int* src = ei;
    const int* dst = ei + E;

    size_t off = 0;
    auto alloc = [&](size_t bytes) -> void* {
        size_t o = (off + 255) & ~(size_t)255;
        off = o + bytes;
        return (void*)((char*)d_ws + o);
    };
    float* dinv = (float*)alloc((size_t)N * 4);
    int*   rowp = (int*)alloc((size_t)N * 4);
    int*   rowe = (int*)alloc((size_t)N * 4);
    int*   bcnt = (int*)alloc((size_t)(B + 1) * 4);
    int*   boff = (int*)alloc((size_t)(B + 1) * 4);
    int*   bcur = (int*)alloc((size_t)(B + 1) * 4);
    int*   ssrc = (int*)alloc((size_t)E * 4);
    float* bufA = (float*)alloc((size_t)N * 128 * 4);
    float* bufB = (float*)alloc((size_t)N * 128 * 4);
    float* aArr = (float*)alloc((size_t)N * 4);
    float* bArr = (float*)alloc((size_t)N * 4);
    (void)ws_size; (void)n_in; (void)out_size;

    // pairs buffer aliased onto bufA (dead until first GEMM writes bufA)
    uint2* pairs = (uint2*)bufA;

    const int gE = (E + 255) / 256;
    const int gR = (N + 63) / 64;

    hipMemsetAsync(bcnt, 0, (size_t)(B + 1) * 4, stream);
    bucket_hist<<<512, 256, 0, stream>>>(dst, bcnt, E, B);
    scan_buckets<<<1, 512, 0, stream>>>(bcnt, boff, bcur, B, E);
    bin_edges<<<(E + BIN_CHUNK - 1) / BIN_CHUNK, 256, 0, stream>>>(src, dst, bcur, pairs, E, B);
    build_csr<<<B, 256, 0, stream>>>(pairs, boff, rowp, rowe, dinv, ssrc, N);

    // layer 1: x(128) -> h1(128)
    gemm_dinv<128, 128, 64, 2><<<gR, 256, 0, stream>>>(x, W1, dinv, bufA, N);
    aggregate<128><<<(N + 7) / 8, 256, 0, stream>>>(bufA, rowp, rowe, ssrc, dinv, b1, bufB, N);
    // layer 2: h1(128) -> h2(64)
    gemm_dinv<128, 64, 32, 2><<<gR, 256, 0, stream>>>(bufB, W2, dinv, bufA, N);
    aggregate<64><<<(N + 15) / 16, 256, 0, stream>>>(bufA, rowp, rowe, ssrc, dinv, b2, bufB, N);
    // layer 3: h2(64) -> h3(32)
    gemm_dinv<64, 32, 32, 1><<<gR, 256, 0, stream>>>(bufB, W3, dinv, bufA, N);
    aggregate<32><<<(N + 31) / 32, 256, 0, stream>>>(bufA, rowp, rowe, ssrc, dinv, b3, bufB, N);

    // edge scoring
    node_scores<<<(N + 7) / 8, 256, 0, stream>>>(bufB, Wc, aArr, bArr, N);
    edge_out<<<gE, 256, 0, stream>>>(src, dst, aArr, bArr, bc, out, E);
}

// Round 3
// 457.389 us; speedup vs baseline: 1.4464x; 1.1790x over previous
//
#include <hip/hip_runtime.h>

// GCN 3-layer + edge scorer for MI355X.
// R2: bucket-binned CSR build (write-combining friendly).
// R3: bf16 message buffers for layer-1/2 aggregates (halves the random-gather
//     bytes on the BW-bound top dispatch); layer-3 stays fp32 (its message
//     error hits the output unattenuated). bin_edges chunk 8192->2048 for
//     CU occupancy (196 -> 782 blocks).

#define BSHIFT 8                      // bucket = dst >> 8  (256 nodes/bucket)
#define MAXB   512                    // LDS sizing; actual B = ceil(N/256) = 391
#define BIN_CHUNK 2048

static __device__ __forceinline__ float4 f4add(float4 a, float4 b) {
    return make_float4(a.x + b.x, a.y + b.y, a.z + b.z, a.w + b.w);
}

// fp32 -> bf16 bits, round-to-nearest-even
static __device__ __forceinline__ unsigned short f2bf(float f) {
    unsigned u = __float_as_uint(f);
    u = (u + 0x7FFFu + ((u >> 16) & 1u)) >> 16;
    return (unsigned short)u;
}

// unpack uint (2 packed bf16) and accumulate
static __device__ __forceinline__ void bfacc2(float& a0, float& a1, unsigned u) {
    a0 += __uint_as_float(u << 16);
    a1 += __uint_as_float(u & 0xFFFF0000u);
}

// ---------------- CSR build ----------------

__global__ __launch_bounds__(256) void bucket_hist(const int* __restrict__ dst,
                                                   int* __restrict__ bcnt,
                                                   int E, int B) {
    __shared__ int h[MAXB];
    const int t = threadIdx.x;
    for (int i = t; i < B; i += 256) h[i] = 0;
    __syncthreads();
    for (int e = blockIdx.x * 256 + t; e < E; e += gridDim.x * 256)
        atomicAdd(&h[dst[e] >> BSHIFT], 1);
    __syncthreads();
    for (int i = t; i < B; i += 256) {
        int c = h[i];
        if (c) atomicAdd(&bcnt[i], c);
    }
}

__global__ __launch_bounds__(512) void scan_buckets(const int* __restrict__ bcnt,
                                                    int* __restrict__ boff,
                                                    int* __restrict__ bcur,
                                                    int B, int E) {
    __shared__ int s[512];
    const int t = threadIdx.x;
    int v = (t < B) ? bcnt[t] : 0;
    s[t] = v;
    __syncthreads();
    #pragma unroll
    for (int off = 1; off < 512; off <<= 1) {
        int add = (t >= off) ? s[t - off] : 0;
        __syncthreads();
        s[t] += add;
        __syncthreads();
    }
    if (t < B) {
        int excl = s[t] - v;
        boff[t] = excl;
        bcur[t] = excl;
    }
    if (t == B - 1) boff[B] = E;
}

__global__ __launch_bounds__(256) void bin_edges(const int* __restrict__ src,
                                                 const int* __restrict__ dst,
                                                 int* __restrict__ bcur,
                                                 uint2* __restrict__ pairs,
                                                 int E, int B) {
    __shared__ int h[MAXB];
    __shared__ int base[MAXB];
    const int t = threadIdx.x;
    const int e0 = blockIdx.x * BIN_CHUNK;
    const int eEnd = min(e0 + BIN_CHUNK, E);
    for (int i = t; i < B; i += 256) h[i] = 0;
    __syncthreads();
    for (int e = e0 + t; e < eEnd; e += 256)
        atomicAdd(&h[dst[e] >> BSHIFT], 1);
    __syncthreads();
    for (int i = t; i < B; i += 256) {
        int c = h[i];
        base[i] = c ? atomicAdd(&bcur[i], c) : 0;
        h[i] = 0;
    }
    __syncthreads();
    for (int e = e0 + t; e < eEnd; e += 256) {
        int d = dst[e];
        int b = d >> BSHIFT;
        int pos = base[b] + atomicAdd(&h[b], 1);
        pairs[pos] = make_uint2((unsigned)src[e], (unsigned)d);
    }
}

__global__ __launch_bounds__(256) void build_csr(const uint2* __restrict__ pairs,
                                                 const int* __restrict__ boff,
                                                 int* __restrict__ rowp,
                                                 int* __restrict__ rowe,
                                                 float* __restrict__ dinv,
                                                 int* __restrict__ ssrc, int N) {
    __shared__ int s[256];
    __shared__ int cur[256];
    const int t = threadIdx.x;
    const int b = blockIdx.x;
    const int eBeg = boff[b], eEnd = boff[b + 1];
    const int nodeBase = b << BSHIFT;
    s[t] = 0;
    __syncthreads();
    for (int e = eBeg + t; e < eEnd; e += 256)
        atomicAdd(&s[pairs[e].y - nodeBase], 1);
    __syncthreads();
    const int v = s[t];
    #pragma unroll
    for (int off = 1; off < 256; off <<= 1) {
        int add = (t >= off) ? s[t - off] : 0;
        __syncthreads();
        s[t] += add;
        __syncthreads();
    }
    const int rp = eBeg + s[t] - v;
    const int node = nodeBase + t;
    if (node < N) {
        rowp[node] = rp;
        rowe[node] = rp + v;
        dinv[node] = rsqrtf((float)(v + 1));
    }
    cur[t] = rp;
    __syncthreads();
    for (int e = eBeg + t; e < eEnd; e += 256) {
        uint2 p = pairs[e];
        int pos = atomicAdd(&cur[p.y - nodeBase], 1);
        ssrc[pos] = (int)p.x;
    }
}

// ---------------- GEMM (X @ W) * dinv ----------------
// OUT_BF16: store G as bf16 bits (ushort) for the bf16 aggregate path.
template <int FIN, int FOUT, int JG, int JT, bool OUT_BF16>
__global__ __launch_bounds__(256) void gemm_dinv(const float* __restrict__ X,
                                                 const float* __restrict__ W,
                                                 const float* __restrict__ dinv,
                                                 void* __restrict__ Gout, int N) {
    constexpr int ROWS = 64;
    constexpr int GROUPS = 256 / JG;
    constexpr int RPT = ROWS / GROUPS;
    __shared__ float xs[ROWS * FIN];
    const int t = threadIdx.x;
    const int r0 = blockIdx.x * ROWS;

    constexpr int NV = ROWS * FIN / 4;
    const float4* X4 = reinterpret_cast<const float4*>(X + (size_t)r0 * FIN);
    float4* xs4 = reinterpret_cast<float4*>(xs);
    #pragma unroll
    for (int v = t; v < NV; v += 256) {
        int row = v / (FIN / 4);
        float4 val = make_float4(0.f, 0.f, 0.f, 0.f);
        if (r0 + row < N) val = X4[v];
        xs4[v] = val;
    }
    __syncthreads();

    const int jg = t % JG;
    const int grp = t / JG;
    float acc[RPT][JT];
    #pragma unroll
    for (int r = 0; r < RPT; r++)
        #pragma unroll
        for (int jj = 0; jj < JT; jj++) acc[r][jj] = 0.f;

    for (int k0 = 0; k0 < FIN; k0 += 8) {
        float wr[8][JT];
        #pragma unroll
        for (int q = 0; q < 8; q++)
            #pragma unroll
            for (int jj = 0; jj < JT; jj++)
                wr[q][jj] = W[(k0 + q) * FOUT + jg + jj * JG];
        #pragma unroll
        for (int r = 0; r < RPT; r++) {
            const int lr = grp * RPT + r;
            float xv[8];
            #pragma unroll
            for (int q = 0; q < 8; q++) xv[q] = xs[lr * FIN + k0 + q];
            #pragma unroll
            for (int q = 0; q < 8; q++)
                #pragma unroll
                for (int jj = 0; jj < JT; jj++)
                    acc[r][jj] += xv[q] * wr[q][jj];
        }
    }

    #pragma unroll
    for (int r = 0; r < RPT; r++) {
        const int gr = r0 + grp * RPT + r;
        if (gr < N) {
            const float dv = dinv[gr];
            #pragma unroll
            for (int jj = 0; jj < JT; jj++) {
                const float val = acc[r][jj] * dv;
                const size_t idx = (size_t)gr * FOUT + jg + jj * JG;
                if (OUT_BF16)
                    ((unsigned short*)Gout)[idx] = f2bf(val);
                else
                    ((float*)Gout)[idx] = val;
            }
        }
    }
}

// ---------------- aggregates ----------------
// bf16 path: G row = F bf16 = 2F bytes; lane owns 8 features (one uint4).
template <int F>
__global__ __launch_bounds__(256) void aggregate_bf16(const unsigned short* __restrict__ G,
                                                      const int* __restrict__ rowp,
                                                      const int* __restrict__ rowe,
                                                      const int* __restrict__ ssrc,
                                                      const float* __restrict__ dinv,
                                                      const float* __restrict__ bias,
                                                      float* __restrict__ H, int N) {
    constexpr int L = F / 8;        // uint4 lanes per node
    constexpr int NPB = 256 / L;
    const int t = threadIdx.x;
    const int lj = t % L;
    const int d = blockIdx.x * NPB + t / L;
    if (d >= N) return;

    const uint4* G4 = reinterpret_cast<const uint4*>(G);
    float a[8];
    #pragma unroll
    for (int i = 0; i < 8; i++) a[i] = 0.f;
    {
        uint4 u = G4[(size_t)d * L + lj];   // self loop
        bfacc2(a[0], a[1], u.x); bfacc2(a[2], a[3], u.y);
        bfacc2(a[4], a[5], u.z); bfacc2(a[6], a[7], u.w);
    }
    int e = rowp[d];
    const int end = rowe[d];
    for (; e + 4 <= end; e += 4) {
        int s0 = ssrc[e], s1 = ssrc[e + 1], s2 = ssrc[e + 2], s3 = ssrc[e + 3];
        uint4 u0 = G4[(size_t)s0 * L + lj];
        uint4 u1 = G4[(size_t)s1 * L + lj];
        uint4 u2 = G4[(size_t)s2 * L + lj];
        uint4 u3 = G4[(size_t)s3 * L + lj];
        bfacc2(a[0], a[1], u0.x); bfacc2(a[2], a[3], u0.y);
        bfacc2(a[4], a[5], u0.z); bfacc2(a[6], a[7], u0.w);
        bfacc2(a[0], a[1], u1.x); bfacc2(a[2], a[3], u1.y);
        bfacc2(a[4], a[5], u1.z); bfacc2(a[6], a[7], u1.w);
        bfacc2(a[0], a[1], u2.x); bfacc2(a[2], a[3], u2.y);
        bfacc2(a[4], a[5], u2.z); bfacc2(a[6], a[7], u2.w);
        bfacc2(a[0], a[1], u3.x); bfacc2(a[2], a[3], u3.y);
        bfacc2(a[4], a[5], u3.z); bfacc2(a[6], a[7], u3.w);
    }
    for (; e < end; e++) {
        uint4 u = G4[(size_t)ssrc[e] * L + lj];
        bfacc2(a[0], a[1], u.x); bfacc2(a[2], a[3], u.y);
        bfacc2(a[4], a[5], u.z); bfacc2(a[6], a[7], u.w);
    }
    const float dv = dinv[d];
    const float4 b0 = reinterpret_cast<const float4*>(bias)[lj * 2];
    const float4 b1 = reinterpret_cast<const float4*>(bias)[lj * 2 + 1];
    float4 h0, h1;
    h0.x = fmaxf(a[0] * dv + b0.x, 0.f);
    h0.y = fmaxf(a[1] * dv + b0.y, 0.f);
    h0.z = fmaxf(a[2] * dv + b0.z, 0.f);
    h0.w = fmaxf(a[3] * dv + b0.w, 0.f);
    h1.x = fmaxf(a[4] * dv + b1.x, 0.f);
    h1.y = fmaxf(a[5] * dv + b1.y, 0.f);
    h1.z = fmaxf(a[6] * dv + b1.z, 0.f);
    h1.w = fmaxf(a[7] * dv + b1.w, 0.f);
    float4* H4 = reinterpret_cast<float4*>(H);
    H4[(size_t)d * (F / 4) + lj * 2]     = h0;
    H4[(size_t)d * (F / 4) + lj * 2 + 1] = h1;
}

// fp32 path (layer 3)
template <int F>
__global__ __launch_bounds__(256) void aggregate_f32(const float* __restrict__ G,
                                                     const int* __restrict__ rowp,
                                                     const int* __restrict__ rowe,
                                                     const int* __restrict__ ssrc,
                                                     const float* __restrict__ dinv,
                                                     const float* __restrict__ bias,
                                                     float* __restrict__ H, int N) {
    constexpr int L = F / 4;
    constexpr int NPB = 256 / L;
    const int t = threadIdx.x;
    const int lj = t % L;
    const int d = blockIdx.x * NPB + t / L;
    if (d >= N) return;

    const float4* G4 = reinterpret_cast<const float4*>(G);
    float4 acc = G4[(size_t)d * L + lj];
    int e = rowp[d];
    const int end = rowe[d];
    for (; e + 4 <= end; e += 4) {
        int s0 = ssrc[e], s1 = ssrc[e + 1], s2 = ssrc[e + 2], s3 = ssrc[e + 3];
        float4 v0 = G4[(size_t)s0 * L + lj];
        float4 v1 = G4[(size_t)s1 * L + lj];
        float4 v2 = G4[(size_t)s2 * L + lj];
        float4 v3 = G4[(size_t)s3 * L + lj];
        acc = f4add(acc, f4add(f4add(v0, v1), f4add(v2, v3)));
    }
    for (; e < end; e++)
        acc = f4add(acc, G4[(size_t)ssrc[e] * L + lj]);
    const float dv = dinv[d];
    const float4 b4 = reinterpret_cast<const float4*>(bias)[lj];
    float4 h;
    h.x = fmaxf(acc.x * dv + b4.x, 0.f);
    h.y = fmaxf(acc.y * dv + b4.y, 0.f);
    h.z = fmaxf(acc.z * dv + b4.z, 0.f);
    h.w = fmaxf(acc.w * dv + b4.w, 0.f);
    reinterpret_cast<float4*>(H)[(size_t)d * L + lj] = h;
}

// ---------------- edge scoring ----------------

__global__ __launch_bounds__(256) void node_scores(const float* __restrict__ H,
                                                   const float* __restrict__ Wc,
                                                   float* __restrict__ aArr,
                                                   float* __restrict__ bArr, int N) {
    const int t = threadIdx.x;
    const int lane = t % 32;
    const int i = blockIdx.x * 8 + t / 32;
    if (i >= N) return;
    const float h = H[(size_t)i * 32 + lane];
    float p = h * Wc[lane];
    float q = h * Wc[32 + lane];
    #pragma unroll
    for (int off = 16; off > 0; off >>= 1) {
        p += __shfl_xor(p, off, 32);
        q += __shfl_xor(q, off, 32);
    }
    if (lane == 0) {
        aArr[i] = p;
        bArr[i] = q;
    }
}

__global__ __launch_bounds__(256) void edge_out(const int* __restrict__ src,
                                                const int* __restrict__ dst,
                                                const float* __restrict__ aArr,
                                                const float* __restrict__ bArr,
                                                const float* __restrict__ bc,
                                                float* __restrict__ out, int E) {
    int e = blockIdx.x * 256 + threadIdx.x;
    if (e < E) out[e] = aArr[src[e]] + bArr[dst[e]] + bc[0];
}

extern "C" void kernel_launch(void* const* d_in, const int* in_sizes, int n_in,
                              void* d_out, int out_size, void* d_ws, size_t ws_size,
                              hipStream_t stream) {
    const float* x  = (const float*)d_in[0];
    const int*   ei = (const int*)d_in[1];
    const float* W1 = (const float*)d_in[2];
    const float* b1 = (const float*)d_in[3];
    const float* W2 = (const float*)d_in[4];
    const float* b2 = (const float*)d_in[5];
    const float* W3 = (const float*)d_in[6];
    const float* b3 = (const float*)d_in[7];
    const float* Wc = (const float*)d_in[8];
    const float* bc = (const float*)d_in[9];
    float* out = (float*)d_out;

    const int N = in_sizes[0] / 128;   // 100000
    const int E = in_sizes[1] / 2;     // 1600000
    const int B = (N + 255) >> BSHIFT; // 391
    const int* src = ei;
    const int* dst = ei + E;

    size_t off = 0;
    auto alloc = [&](size_t bytes) -> void* {
        size_t o = (off + 255) & ~(size_t)255;
        off = o + bytes;
        return (void*)((char*)d_ws + o);
    };
    float* dinv = (float*)alloc((size_t)N * 4);
    int*   rowp = (int*)alloc((size_t)N * 4);
    int*   rowe = (int*)alloc((size_t)N * 4);
    int*   bcnt = (int*)alloc((size_t)(B + 1) * 4);
    int*   boff = (int*)alloc((size_t)(B + 1) * 4);
    int*   bcur = (int*)alloc((size_t)(B + 1) * 4);
    int*   ssrc = (int*)alloc((size_t)E * 4);
    float* bufA = (float*)alloc((size_t)N * 128 * 4);
    float* bufB = (float*)alloc((size_t)N * 128 * 4);
    float* aArr = (float*)alloc((size_t)N * 4);
    float* bArr = (float*)alloc((size_t)N * 4);
    (void)ws_size; (void)n_in; (void)out_size;

    uint2* pairs = (uint2*)bufA;               // dead until first GEMM
    unsigned short* g16 = (unsigned short*)bufA; // bf16 message buffer (layers 1,2)

    const int gE = (E + 255) / 256;
    const int gR = (N + 63) / 64;

    hipMemsetAsync(bcnt, 0, (size_t)(B + 1) * 4, stream);
    bucket_hist<<<512, 256, 0, stream>>>(dst, bcnt, E, B);
    scan_buckets<<<1, 512, 0, stream>>>(bcnt, boff, bcur, B, E);
    bin_edges<<<(E + BIN_CHUNK - 1) / BIN_CHUNK, 256, 0, stream>>>(src, dst, bcur, pairs, E, B);
    build_csr<<<B, 256, 0, stream>>>(pairs, boff, rowp, rowe, dinv, ssrc, N);

    // layer 1: x(128) -> h1(128), bf16 messages
    gemm_dinv<128, 128, 64, 2, true><<<gR, 256, 0, stream>>>(x, W1, dinv, g16, N);
    aggregate_bf16<128><<<(N + 15) / 16, 256, 0, stream>>>(g16, rowp, rowe, ssrc, dinv, b1, bufB, N);
    // layer 2: h1(128) -> h2(64), bf16 messages
    gemm_dinv<128, 64, 32, 2, true><<<gR, 256, 0, stream>>>(bufB, W2, dinv, g16, N);
    aggregate_bf16<64><<<(N + 31) / 32, 256, 0, stream>>>(g16, rowp, rowe, ssrc, dinv, b2, bufB, N);
    // layer 3: h2(64) -> h3(32), fp32 messages (error hits output unattenuated)
    gemm_dinv<64, 32, 32, 1, false><<<gR, 256, 0, stream>>>(bufB, W3, dinv, bufA, N);
    aggregate_f32<32><<<(N + 31) / 32, 256, 0, stream>>>(bufA, rowp, rowe, ssrc, dinv, b3, bufB, N);

    // edge scoring
    node_scores<<<(N + 7) / 8, 256, 0, stream>>>(bufB, Wc, aArr, bArr, N);
    edge_out<<<gE, 256, 0, stream>>>(src, dst, aArr, bArr, bc, out, E);
}

// Round 4
// 412.969 us; speedup vs baseline: 1.6019x; 1.1076x over previous
//
#include <hip/hip_runtime.h>

// GCN 3-layer + edge scorer for MI355X.
// R2: bucket-binned CSR build. R3: bf16 message buffers for L1/L2 aggregates.
// R4: bf16 MFMA (16x16x32) for GEMM layers 1-2 (fp32 vector GEMM was
//     LDS-throughput-bound at 29% peak); h1 stored bf16 (only consumer is the
//     bf16 L2 GEMM -> identical numerics, saves 51MB traffic). Layer 3 GEMM
//     stays fp32 vector: its rounding error hits the output unattenuated.

typedef unsigned short u16;
typedef short bfrag __attribute__((ext_vector_type(8)));   // 8 bf16 = 4 VGPR
typedef float ffrag __attribute__((ext_vector_type(4)));   // 4 f32 acc

#define BSHIFT 8
#define MAXB   512
#define BIN_CHUNK 2048

static __device__ __forceinline__ float4 f4add(float4 a, float4 b) {
    return make_float4(a.x + b.x, a.y + b.y, a.z + b.z, a.w + b.w);
}

// fp32 -> bf16 bits, RNE
static __device__ __forceinline__ u16 f2bf(float f) {
    unsigned u = __float_as_uint(f);
    u = (u + 0x7FFFu + ((u >> 16) & 1u)) >> 16;
    return (u16)u;
}

static __device__ __forceinline__ void bfacc2(float& a0, float& a1, unsigned u) {
    a0 += __uint_as_float(u << 16);
    a1 += __uint_as_float(u & 0xFFFF0000u);
}

// ---------------- CSR build ----------------

__global__ __launch_bounds__(256) void bucket_hist(const int* __restrict__ dst,
                                                   int* __restrict__ bcnt,
                                                   int E, int B) {
    __shared__ int h[MAXB];
    const int t = threadIdx.x;
    for (int i = t; i < B; i += 256) h[i] = 0;
    __syncthreads();
    for (int e = blockIdx.x * 256 + t; e < E; e += gridDim.x * 256)
        atomicAdd(&h[dst[e] >> BSHIFT], 1);
    __syncthreads();
    for (int i = t; i < B; i += 256) {
        int c = h[i];
        if (c) atomicAdd(&bcnt[i], c);
    }
}

__global__ __launch_bounds__(512) void scan_buckets(const int* __restrict__ bcnt,
                                                    int* __restrict__ boff,
                                                    int* __restrict__ bcur,
                                                    int B, int E) {
    __shared__ int s[512];
    const int t = threadIdx.x;
    int v = (t < B) ? bcnt[t] : 0;
    s[t] = v;
    __syncthreads();
    #pragma unroll
    for (int off = 1; off < 512; off <<= 1) {
        int add = (t >= off) ? s[t - off] : 0;
        __syncthreads();
        s[t] += add;
        __syncthreads();
    }
    if (t < B) {
        int excl = s[t] - v;
        boff[t] = excl;
        bcur[t] = excl;
    }
    if (t == B - 1) boff[B] = E;
}

__global__ __launch_bounds__(256) void bin_edges(const int* __restrict__ src,
                                                 const int* __restrict__ dst,
                                                 int* __restrict__ bcur,
                                                 uint2* __restrict__ pairs,
                                                 int E, int B) {
    __shared__ int h[MAXB];
    __shared__ int base[MAXB];
    const int t = threadIdx.x;
    const int e0 = blockIdx.x * BIN_CHUNK;
    const int eEnd = min(e0 + BIN_CHUNK, E);
    for (int i = t; i < B; i += 256) h[i] = 0;
    __syncthreads();
    for (int e = e0 + t; e < eEnd; e += 256)
        atomicAdd(&h[dst[e] >> BSHIFT], 1);
    __syncthreads();
    for (int i = t; i < B; i += 256) {
        int c = h[i];
        base[i] = c ? atomicAdd(&bcur[i], c) : 0;
        h[i] = 0;
    }
    __syncthreads();
    for (int e = e0 + t; e < eEnd; e += 256) {
        int d = dst[e];
        int b = d >> BSHIFT;
        int pos = base[b] + atomicAdd(&h[b], 1);
        pairs[pos] = make_uint2((unsigned)src[e], (unsigned)d);
    }
}

__global__ __launch_bounds__(256) void build_csr(const uint2* __restrict__ pairs,
                                                 const int* __restrict__ boff,
                                                 int* __restrict__ rowp,
                                                 int* __restrict__ rowe,
                                                 float* __restrict__ dinv,
                                                 int* __restrict__ ssrc, int N) {
    __shared__ int s[256];
    __shared__ int cur[256];
    const int t = threadIdx.x;
    const int b = blockIdx.x;
    const int eBeg = boff[b], eEnd = boff[b + 1];
    const int nodeBase = b << BSHIFT;
    s[t] = 0;
    __syncthreads();
    for (int e = eBeg + t; e < eEnd; e += 256)
        atomicAdd(&s[pairs[e].y - nodeBase], 1);
    __syncthreads();
    const int v = s[t];
    #pragma unroll
    for (int off = 1; off < 256; off <<= 1) {
        int add = (t >= off) ? s[t - off] : 0;
        __syncthreads();
        s[t] += add;
        __syncthreads();
    }
    const int rp = eBeg + s[t] - v;
    const int node = nodeBase + t;
    if (node < N) {
        rowp[node] = rp;
        rowe[node] = rp + v;
        dinv[node] = rsqrtf((float)(v + 1));
    }
    cur[t] = rp;
    __syncthreads();
    for (int e = eBeg + t; e < eEnd; e += 256) {
        uint2 p = pairs[e];
        int pos = atomicAdd(&cur[p.y - nodeBase], 1);
        ssrc[pos] = (int)p.x;
    }
}

// ---------------- W prep: Wt[n][k] = bf16(W[k][n]) ----------------
__global__ __launch_bounds__(256) void prep_w(const float* __restrict__ W,
                                              u16* __restrict__ Wt, int K, int Nc) {
    int idx = blockIdx.x * 256 + threadIdx.x;
    if (idx < K * Nc) {
        int n = idx / K, k = idx - n * K;
        Wt[idx] = f2bf(W[(size_t)k * Nc + n]);
    }
}

// ---------------- MFMA GEMM: G = bf16((X @ W) * dinv[row]) ----------------
// Block = 256 thr (4 waves), tile 64 rows x FOUT. Whole Wt kept in B-frag
// registers (loaded once). A staged to LDS bf16 with XOR-swizzled 16B blocks.
// mfma_f32_16x16x32_bf16: A[m=lane&15][k=quad*8+j]; B[k=quad*8+j][n=lane&15];
// D: row=quad*4+reg, col=lane&15 (guide §3, HW-verified layouts).
template <int FIN, int FOUT, bool AF32, int MINW>
__global__ __launch_bounds__(256, MINW)
void gemm_mfma(const void* __restrict__ Xv, const u16* __restrict__ Wt,
               const float* __restrict__ dinv, u16* __restrict__ G, int N) {
    constexpr int NT = FOUT / 16;       // col tiles per wave
    constexpr int KK = FIN / 32;        // K steps
    constexpr int CB = FIN / 8;         // 16B blocks per A row
    constexpr int ITER = (64 * CB) / 256;
    __shared__ __align__(16) u16 xs[64 * FIN];
    __shared__ float ldv[64];

    const int t = threadIdx.x;
    const int wave = t >> 6;
    const int lane = t & 63;
    const int l15 = lane & 15;
    const int quad = lane >> 4;
    const int r0 = blockIdx.x * 64;

    // B fragments: entire Wt -> registers (L1/L2-hot, loaded once per block)
    bfrag Bf[NT][KK];
    #pragma unroll
    for (int nt = 0; nt < NT; nt++)
        #pragma unroll
        for (int kk = 0; kk < KK; kk++)
            Bf[nt][kk] = *reinterpret_cast<const bfrag*>(
                &Wt[(size_t)(nt * 16 + l15) * FIN + kk * 32 + quad * 8]);

    if (t < 64) ldv[t] = (r0 + t < N) ? dinv[r0 + t] : 0.f;

    // stage A tile as bf16, block cb stored at cb ^ (row & 7)
    #pragma unroll
    for (int i = 0; i < ITER; i++) {
        int v = t + 256 * i;
        int row = v / CB;
        int cb = v - row * CB;
        uint4 pack = make_uint4(0, 0, 0, 0);
        if (r0 + row < N) {
            if (AF32) {
                const float* X = (const float*)Xv;
                const float4* p = reinterpret_cast<const float4*>(
                    &X[(size_t)(r0 + row) * FIN + cb * 8]);
                float4 lo = p[0], hi = p[1];
                pack.x = f2bf(lo.x) | ((unsigned)f2bf(lo.y) << 16);
                pack.y = f2bf(lo.z) | ((unsigned)f2bf(lo.w) << 16);
                pack.z = f2bf(hi.x) | ((unsigned)f2bf(hi.y) << 16);
                pack.w = f2bf(hi.z) | ((unsigned)f2bf(hi.w) << 16);
            } else {
                const u16* X = (const u16*)Xv;
                pack = *reinterpret_cast<const uint4*>(
                    &X[(size_t)(r0 + row) * FIN + cb * 8]);
            }
        }
        int cbs = cb ^ (row & 7);
        *reinterpret_cast<uint4*>(&xs[row * FIN + cbs * 8]) = pack;
    }
    __syncthreads();

    ffrag acc[NT];
    #pragma unroll
    for (int nt = 0; nt < NT; nt++) {
        acc[nt][0] = 0.f; acc[nt][1] = 0.f; acc[nt][2] = 0.f; acc[nt][3] = 0.f;
    }

    const int arow = wave * 16 + l15;
    #pragma unroll
    for (int kk = 0; kk < KK; kk++) {
        int cb = (kk * 4 + quad) ^ (l15 & 7);   // arow&7 == l15&7
        bfrag a = *reinterpret_cast<const bfrag*>(&xs[arow * FIN + cb * 8]);
        #pragma unroll
        for (int nt = 0; nt < NT; nt++)
            acc[nt] = __builtin_amdgcn_mfma_f32_16x16x32_bf16(a, Bf[nt][kk], acc[nt], 0, 0, 0);
    }

    #pragma unroll
    for (int nt = 0; nt < NT; nt++)
        #pragma unroll
        for (int r = 0; r < 4; r++) {
            int rl = wave * 16 + quad * 4 + r;
            int grow = r0 + rl;
            if (grow < N)
                G[(size_t)grow * FOUT + nt * 16 + l15] = f2bf(acc[nt][r] * ldv[rl]);
        }
}

// ---------------- aggregates ----------------
template <int F, bool OUT_BF16>
__global__ __launch_bounds__(256) void aggregate_bf16(const u16* __restrict__ G,
                                                      const int* __restrict__ rowp,
                                                      const int* __restrict__ rowe,
                                                      const int* __restrict__ ssrc,
                                                      const float* __restrict__ dinv,
                                                      const float* __restrict__ bias,
                                                      void* __restrict__ Hout, int N) {
    constexpr int L = F / 8;
    constexpr int NPB = 256 / L;
    const int t = threadIdx.x;
    const int lj = t % L;
    const int d = blockIdx.x * NPB + t / L;
    if (d >= N) return;

    const uint4* G4 = reinterpret_cast<const uint4*>(G);
    float a[8];
    #pragma unroll
    for (int i = 0; i < 8; i++) a[i] = 0.f;
    {
        uint4 u = G4[(size_t)d * L + lj];
        bfacc2(a[0], a[1], u.x); bfacc2(a[2], a[3], u.y);
        bfacc2(a[4], a[5], u.z); bfacc2(a[6], a[7], u.w);
    }
    int e = rowp[d];
    const int end = rowe[d];
    for (; e + 4 <= end; e += 4) {
        int s0 = ssrc[e], s1 = ssrc[e + 1], s2 = ssrc[e + 2], s3 = ssrc[e + 3];
        uint4 u0 = G4[(size_t)s0 * L + lj];
        uint4 u1 = G4[(size_t)s1 * L + lj];
        uint4 u2 = G4[(size_t)s2 * L + lj];
        uint4 u3 = G4[(size_t)s3 * L + lj];
        bfacc2(a[0], a[1], u0.x); bfacc2(a[2], a[3], u0.y);
        bfacc2(a[4], a[5], u0.z); bfacc2(a[6], a[7], u0.w);
        bfacc2(a[0], a[1], u1.x); bfacc2(a[2], a[3], u1.y);
        bfacc2(a[4], a[5], u1.z); bfacc2(a[6], a[7], u1.w);
        bfacc2(a[0], a[1], u2.x); bfacc2(a[2], a[3], u2.y);
        bfacc2(a[4], a[5], u2.z); bfacc2(a[6], a[7], u2.w);
        bfacc2(a[0], a[1], u3.x); bfacc2(a[2], a[3], u3.y);
        bfacc2(a[4], a[5], u3.z); bfacc2(a[6], a[7], u3.w);
    }
    for (; e < end; e++) {
        uint4 u = G4[(size_t)ssrc[e] * L + lj];
        bfacc2(a[0], a[1], u.x); bfacc2(a[2], a[3], u.y);
        bfacc2(a[4], a[5], u.z); bfacc2(a[6], a[7], u.w);
    }
    const float dv = dinv[d];
    const float4 b0 = reinterpret_cast<const float4*>(bias)[lj * 2];
    const float4 b1 = reinterpret_cast<const float4*>(bias)[lj * 2 + 1];
    float h[8];
    h[0] = fmaxf(a[0] * dv + b0.x, 0.f);
    h[1] = fmaxf(a[1] * dv + b0.y, 0.f);
    h[2] = fmaxf(a[2] * dv + b0.z, 0.f);
    h[3] = fmaxf(a[3] * dv + b0.w, 0.f);
    h[4] = fmaxf(a[4] * dv + b1.x, 0.f);
    h[5] = fmaxf(a[5] * dv + b1.y, 0.f);
    h[6] = fmaxf(a[6] * dv + b1.z, 0.f);
    h[7] = fmaxf(a[7] * dv + b1.w, 0.f);
    if (OUT_BF16) {
        uint4 pk;
        pk.x = f2bf(h[0]) | ((unsigned)f2bf(h[1]) << 16);
        pk.y = f2bf(h[2]) | ((unsigned)f2bf(h[3]) << 16);
        pk.z = f2bf(h[4]) | ((unsigned)f2bf(h[5]) << 16);
        pk.w = f2bf(h[6]) | ((unsigned)f2bf(h[7]) << 16);
        reinterpret_cast<uint4*>(Hout)[(size_t)d * L + lj] = pk;
    } else {
        float4* H4 = reinterpret_cast<float4*>(Hout);
        H4[(size_t)d * (F / 4) + lj * 2]     = make_float4(h[0], h[1], h[2], h[3]);
        H4[(size_t)d * (F / 4) + lj * 2 + 1] = make_float4(h[4], h[5], h[6], h[7]);
    }
}

template <int F>
__global__ __launch_bounds__(256) void aggregate_f32(const float* __restrict__ G,
                                                     const int* __restrict__ rowp,
                                                     const int* __restrict__ rowe,
                                                     const int* __restrict__ ssrc,
                                                     const float* __restrict__ dinv,
                                                     const float* __restrict__ bias,
                                                     float* __restrict__ H, int N) {
    constexpr int L = F / 4;
    constexpr int NPB = 256 / L;
    const int t = threadIdx.x;
    const int lj = t % L;
    const int d = blockIdx.x * NPB + t / L;
    if (d >= N) return;

    const float4* G4 = reinterpret_cast<const float4*>(G);
    float4 acc = G4[(size_t)d * L + lj];
    int e = rowp[d];
    const int end = rowe[d];
    for (; e + 4 <= end; e += 4) {
        int s0 = ssrc[e], s1 = ssrc[e + 1], s2 = ssrc[e + 2], s3 = ssrc[e + 3];
        float4 v0 = G4[(size_t)s0 * L + lj];
        float4 v1 = G4[(size_t)s1 * L + lj];
        float4 v2 = G4[(size_t)s2 * L + lj];
        float4 v3 = G4[(size_t)s3 * L + lj];
        acc = f4add(acc, f4add(f4add(v0, v1), f4add(v2, v3)));
    }
    for (; e < end; e++)
        acc = f4add(acc, G4[(size_t)ssrc[e] * L + lj]);
    const float dv = dinv[d];
    const float4 b4 = reinterpret_cast<const float4*>(bias)[lj];
    float4 h;
    h.x = fmaxf(acc.x * dv + b4.x, 0.f);
    h.y = fmaxf(acc.y * dv + b4.y, 0.f);
    h.z = fmaxf(acc.z * dv + b4.z, 0.f);
    h.w = fmaxf(acc.w * dv + b4.w, 0.f);
    reinterpret_cast<float4*>(H)[(size_t)d * L + lj] = h;
}

// ---------------- fp32 vector GEMM (layer 3 only) ----------------
template <int FIN, int FOUT, int JG, int JT>
__global__ __launch_bounds__(256) void gemm_dinv(const float* __restrict__ X,
                                                 const float* __restrict__ W,
                                                 const float* __restrict__ dinv,
                                                 float* __restrict__ G, int N) {
    constexpr int ROWS = 64;
    constexpr int GROUPS = 256 / JG;
    constexpr int RPT = ROWS / GROUPS;
    __shared__ float xs[ROWS * FIN];
    const int t = threadIdx.x;
    const int r0 = blockIdx.x * ROWS;

    constexpr int NV = ROWS * FIN / 4;
    const float4* X4 = reinterpret_cast<const float4*>(X + (size_t)r0 * FIN);
    float4* xs4 = reinterpret_cast<float4*>(xs);
    #pragma unroll
    for (int v = t; v < NV; v += 256) {
        int row = v / (FIN / 4);
        float4 val = make_float4(0.f, 0.f, 0.f, 0.f);
        if (r0 + row < N) val = X4[v];
        xs4[v] = val;
    }
    __syncthreads();

    const int jg = t % JG;
    const int grp = t / JG;
    float acc[RPT][JT];
    #pragma unroll
    for (int r = 0; r < RPT; r++)
        #pragma unroll
        for (int jj = 0; jj < JT; jj++) acc[r][jj] = 0.f;

    for (int k0 = 0; k0 < FIN; k0 += 8) {
        float wr[8][JT];
        #pragma unroll
        for (int q = 0; q < 8; q++)
            #pragma unroll
            for (int jj = 0; jj < JT; jj++)
                wr[q][jj] = W[(k0 + q) * FOUT + jg + jj * JG];
        #pragma unroll
        for (int r = 0; r < RPT; r++) {
            const int lr = grp * RPT + r;
            float xv[8];
            #pragma unroll
            for (int q = 0; q < 8; q++) xv[q] = xs[lr * FIN + k0 + q];
            #pragma unroll
            for (int q = 0; q < 8; q++)
                #pragma unroll
                for (int jj = 0; jj < JT; jj++)
                    acc[r][jj] += xv[q] * wr[q][jj];
        }
    }

    #pragma unroll
    for (int r = 0; r < RPT; r++) {
        const int gr = r0 + grp * RPT + r;
        if (gr < N) {
            const float dv = dinv[gr];
            #pragma unroll
            for (int jj = 0; jj < JT; jj++)
                G[(size_t)gr * FOUT + jg + jj * JG] = acc[r][jj] * dv;
        }
    }
}

// ---------------- edge scoring ----------------

__global__ __launch_bounds__(256) void node_scores(const float* __restrict__ H,
                                                   const float* __restrict__ Wc,
                                                   float* __restrict__ aArr,
                                                   float* __restrict__ bArr, int N) {
    const int t = threadIdx.x;
    const int lane = t % 32;
    const int i = blockIdx.x * 8 + t / 32;
    if (i >= N) return;
    const float h = H[(size_t)i * 32 + lane];
    float p = h * Wc[lane];
    float q = h * Wc[32 + lane];
    #pragma unroll
    for (int off = 16; off > 0; off >>= 1) {
        p += __shfl_xor(p, off, 32);
        q += __shfl_xor(q, off, 32);
    }
    if (lane == 0) {
        aArr[i] = p;
        bArr[i] = q;
    }
}

__global__ __launch_bounds__(256) void edge_out(const int* __restrict__ src,
                                                const int* __restrict__ dst,
                                                const float* __restrict__ aArr,
                                                const float* __restrict__ bArr,
                                                const float* __restrict__ bc,
                                                float* __restrict__ out, int E) {
    int e = blockIdx.x * 256 + threadIdx.x;
    if (e < E) out[e] = aArr[src[e]] + bArr[dst[e]] + bc[0];
}

extern "C" void kernel_launch(void* const* d_in, const int* in_sizes, int n_in,
                              void* d_out, int out_size, void* d_ws, size_t ws_size,
                              hipStream_t stream) {
    const float* x  = (const float*)d_in[0];
    const int*   ei = (const int*)d_in[1];
    const float* W1 = (const float*)d_in[2];
    const float* b1 = (const float*)d_in[3];
    const float* W2 = (const float*)d_in[4];
    const float* b2 = (const float*)d_in[5];
    const float* W3 = (const float*)d_in[6];
    const float* b3 = (const float*)d_in[7];
    const float* Wc = (const float*)d_in[8];
    const float* bc = (const float*)d_in[9];
    float* out = (float*)d_out;

    const int N = in_sizes[0] / 128;   // 100000
    const int E = in_sizes[1] / 2;     // 1600000
    const int B = (N + 255) >> BSHIFT; // 391
    const int* src = ei;
    const int* dst = ei + E;

    size_t off = 0;
    auto alloc = [&](size_t bytes) -> void* {
        size_t o = (off + 255) & ~(size_t)255;
        off = o + bytes;
        return (void*)((char*)d_ws + o);
    };
    float* dinv = (float*)alloc((size_t)N * 4);
    int*   rowp = (int*)alloc((size_t)N * 4);
    int*   rowe = (int*)alloc((size_t)N * 4);
    int*   bcnt = (int*)alloc((size_t)(B + 1) * 4);
    int*   boff = (int*)alloc((size_t)(B + 1) * 4);
    int*   bcur = (int*)alloc((size_t)(B + 1) * 4);
    int*   ssrc = (int*)alloc((size_t)E * 4);
    u16*   w1t  = (u16*)alloc(128 * 128 * 2);
    u16*   w2t  = (u16*)alloc(128 * 64 * 2);
    u16*   g16  = (u16*)alloc((size_t)N * 128 * 2);   // messages L1/L2; g3f alias
    u16*   h1b  = (u16*)alloc((size_t)N * 128 * 2);   // h1 bf16; pairs + h3f alias
    float* h2f  = (float*)alloc((size_t)N * 64 * 4);  // h2 fp32
    float* aArr = (float*)alloc((size_t)N * 4);
    float* bArr = (float*)alloc((size_t)N * 4);
    (void)ws_size; (void)n_in; (void)out_size;

    uint2* pairs = (uint2*)h1b;     // dead before L1 aggregate writes h1b
    float* g3f   = (float*)g16;     // g16 dead after L2 aggregate
    float* h3f   = (float*)h1b;     // h1b dead after L2 gemm

    const int gE = (E + 255) / 256;
    const int gR = (N + 63) / 64;   // 1563

    hipMemsetAsync(bcnt, 0, (size_t)(B + 1) * 4, stream);
    bucket_hist<<<512, 256, 0, stream>>>(dst, bcnt, E, B);
    scan_buckets<<<1, 512, 0, stream>>>(bcnt, boff, bcur, B, E);
    bin_edges<<<(E + BIN_CHUNK - 1) / BIN_CHUNK, 256, 0, stream>>>(src, dst, bcur, pairs, E, B);
    build_csr<<<B, 256, 0, stream>>>(pairs, boff, rowp, rowe, dinv, ssrc, N);

    prep_w<<<64, 256, 0, stream>>>(W1, w1t, 128, 128);
    prep_w<<<32, 256, 0, stream>>>(W2, w2t, 128, 64);

    // layer 1: x(f32,128) -> MFMA -> g16 -> agg -> h1 (bf16)
    gemm_mfma<128, 128, true, 2><<<gR, 256, 0, stream>>>(x, w1t, dinv, g16, N);
    aggregate_bf16<128, true><<<(N + 15) / 16, 256, 0, stream>>>(g16, rowp, rowe, ssrc, dinv, b1, h1b, N);
    // layer 2: h1(bf16,128) -> MFMA -> g16 -> agg -> h2 (fp32)
    gemm_mfma<128, 64, false, 4><<<gR, 256, 0, stream>>>(h1b, w2t, dinv, g16, N);
    aggregate_bf16<64, false><<<(N + 31) / 32, 256, 0, stream>>>(g16, rowp, rowe, ssrc, dinv, b2, h2f, N);
    // layer 3: h2(f32,64) -> fp32 vector GEMM -> g3f -> agg -> h3 (fp32)
    gemm_dinv<64, 32, 32, 1><<<gR, 256, 0, stream>>>(h2f, W3, dinv, g3f, N);
    aggregate_f32<32><<<(N + 31) / 32, 256, 0, stream>>>(g3f, rowp, rowe, ssrc, dinv, b3, h3f, N);

    // edge scoring
    node_scores<<<(N + 7) / 8, 256, 0, stream>>>(h3f, Wc, aArr, bArr, N);
    edge_out<<<gE, 256, 0, stream>>>(src, dst, aArr, bArr, bc, out, E);
}